// Round 1
// baseline (2334.078 us; speedup 1.0000x reference)
//
#include <hip/hip_runtime.h>

// Problem: B=64, T=512, E=8192 fp32. out[b][j] = mean of anti-diagonal
// s = T+j of inputs[b]:  sum_{r=max(0,j-7679)}^{511} in[b][r][T+j-r] / min(512, 8191-j)
// Flat addr: b*T*E + (T+j) + r*(E-1)  -> consecutive j = consecutive addresses
// => coalesced wave loads; each used input element read exactly once (streaming).

constexpr int B_   = 64;
constexpr int T_   = 512;
constexpr int E_   = 8192;
constexpr int JTOT = E_ - 1;          // 8191 outputs per batch row
constexpr int BLK  = 256;             // threads per block
constexpr int KPT  = 4;              // j's per thread (spaced BLK apart)
constexpr int JBLK = BLK * KPT;       // 1024 j's per block
constexpr int NJB  = E_ / JBLK;       // 8 j-blocks per batch (covers j in [0,8192))

__global__ __launch_bounds__(BLK)
void antidiag_mean_kernel(const float* __restrict__ in, float* __restrict__ out) {
    const int b   = blockIdx.x >> 3;          // / NJB
    const int jb  = blockIdx.x & (NJB - 1);
    const int tid = threadIdx.x;
    const int j0  = jb * JBLK + tid;          // j for k=0; k-th j = j0 + k*BLK

    // base address for r=0, k=0
    const float* base = in + (size_t)b * T_ * E_ + T_ + j0;

    float acc[KPT];
    #pragma unroll
    for (int k = 0; k < KPT; ++k) acc[k] = 0.0f;

    if (jb != NJB - 1) {
        // Clean path: all j <= 7679+... (max j here = 7*1024-1 = 7167 < 7679),
        // so every r in [0,512) is valid. 4 coalesced streams per thread.
        const float* p = base;
        #pragma unroll 4
        for (int r = 0; r < T_; ++r) {
            #pragma unroll
            for (int k = 0; k < KPT; ++k) acc[k] += p[k * BLK];
            p += (E_ - 1);
        }
    } else {
        // Ragged edge: j in [7168, 8191]. Diagonal s=T+j needs c=T+j-r <= E-1,
        // i.e. r >= j - 7679. j == 8191 is out of range (output width 8191).
        #pragma unroll
        for (int k = 0; k < KPT; ++k) {
            const int jk = j0 + k * BLK;
            if (jk > JTOT - 1) continue;      // jk == 8191: no output
            int rstart = jk - (E_ - 1 - T_);  // jk - 7679
            if (rstart < 0) rstart = 0;
            const float* p = base + k * BLK + (size_t)rstart * (E_ - 1);
            float a = 0.0f;
            for (int r = rstart; r < T_; ++r) { a += *p; p += (E_ - 1); }
            acc[k] = a;
        }
    }

    // Store: coalesced per k. count = min(512, 8191 - j)
    #pragma unroll
    for (int k = 0; k < KPT; ++k) {
        const int jk = j0 + k * BLK;
        if (jk < JTOT) {
            int cnt = JTOT - jk;
            if (cnt > T_) cnt = T_;
            out[(size_t)b * JTOT + jk] = acc[k] * (1.0f / (float)cnt);
        }
    }
}

extern "C" void kernel_launch(void* const* d_in, const int* in_sizes, int n_in,
                              void* d_out, int out_size, void* d_ws, size_t ws_size,
                              hipStream_t stream) {
    const float* in = (const float*)d_in[0];
    float* out = (float*)d_out;
    dim3 grid(B_ * NJB);   // 512 blocks
    dim3 block(BLK);
    antidiag_mean_kernel<<<grid, block, 0, stream>>>(in, out);
}